// Round 9
// baseline (566.567 us; speedup 1.0000x reference)
//
#include <hip/hip_runtime.h>
#include <hip/hip_bf16.h>
#include <math.h>

#define N_NODES 10000
#define N_EDGES 80000
#define N_ORI   12
#define N_ROWS  (N_NODES * N_ORI)

typedef __attribute__((ext_vector_type(8))) short bfrag;   // 8 bf16 = 4 VGPRs
typedef __attribute__((ext_vector_type(4))) float f32x4;

// fast gelu (tanh-approx, overflow-safe); |err| < ~3e-3 < bf16 ulp downstream.
// exp2 form: log2(e) folded into the leading constant (one fewer v_mul than
// __expf; identical hardware op v_exp_f32).
__device__ __forceinline__ float gelu_f(float x) {
    float u = 2.3022081975f * x * (1.0f + 0.044715f * x * x);
    float e = exp2f(-u);
    return x * __builtin_amdgcn_rcpf(1.0f + e);
}
// exact gelu for the tiny f32-precision ori path
__device__ __forceinline__ float gelu_exact(float x) {
    return 0.5f * x * (1.0f + erff(x * 0.70710678118654752440f));
}
// NOTE: keep the compiler's __float2bfloat16 path. Inline-asm cvt_pk failed
// correctness (round 6, absmax 468). NEVER pass local arrays by pointer into
// pack helpers: round 7 showed that sends the array to scratch (+120MB HBM
// traffic in node_mfma, rule #20). Use inline union loops with constant idx.
__device__ __forceinline__ short f2bf(float x) {
    __hip_bfloat16 h = __float2bfloat16(x);
    return *reinterpret_cast<short*>(&h);
}
__device__ __forceinline__ float bflo(unsigned u) { return __uint_as_float(u << 16); }
__device__ __forceinline__ float bfhi(unsigned u) { return __uint_as_float(u & 0xffff0000u); }

// pack 4 f32 (by value) -> 4 bf16 in memory order
__device__ __forceinline__ int2 pack4(float a, float b, float c, float d) {
    union { short s[4]; int2 v; } u;
    u.s[0] = f2bf(a); u.s[1] = f2bf(b); u.s[2] = f2bf(c); u.s[3] = f2bf(d);
    return u.v;
}

// ---------------------------------------------------------------------------
// CSR build (dst-sorted edge list for gathers)
// ---------------------------------------------------------------------------
__global__ __launch_bounds__(256) void csr_count(
    const int* __restrict__ ei, int* __restrict__ deg)
{
    int e = blockIdx.x*256 + threadIdx.x;
    if (e < N_EDGES) atomicAdd(&deg[ei[N_EDGES + e]], 1);
}

__global__ __launch_bounds__(256) void csr_scan(
    const int* __restrict__ deg, int* __restrict__ rp, int* __restrict__ wp)
{
    __shared__ int part[256];
    __shared__ int sbase[257];
    int t = threadIdx.x;
    int cs = t*40;
    int sum = 0;
    for (int i = 0; i < 40; i++) { int idx = cs+i; if (idx < N_NODES) sum += deg[idx]; }
    part[t] = sum;
    __syncthreads();
    if (t == 0) {
        int run = 0;
        for (int i = 0; i < 256; i++) { sbase[i] = run; run += part[i]; }
        sbase[256] = run;
    }
    __syncthreads();
    int run = sbase[t];
    for (int i = 0; i < 40; i++) {
        int idx = cs+i;
        if (idx < N_NODES) { rp[idx] = run; wp[idx] = run; run += deg[idx]; }
    }
    if (t == 0) rp[N_NODES] = sbase[256];
}

__global__ __launch_bounds__(256) void csr_fill(
    const int* __restrict__ ei, int* __restrict__ wp,
    int* __restrict__ dstOf, int* __restrict__ srcOf)
{
    int e = blockIdx.x*256 + threadIdx.x;
    if (e >= N_EDGES) return;
    int dn = ei[N_EDGES + e];
    int j = atomicAdd(&wp[dn], 1);
    dstOf[j] = dn;
    srcOf[j] = ei[e];
}

// ---------------------------------------------------------------------------
// K0 (fused setup): blocks 0-3 weight prep; 4-39 ori MLP+fk; 40-2539 embed.
// Weight buffers stored in PER-LANE FRAGMENT ORDER: W'[frag][lane][8] so MFMA
// operand loads are contiguous 1KB per wave instruction.
// ---------------------------------------------------------------------------
__global__ __launch_bounds__(256) void setup_kernel(
    const float* __restrict__ W1, const float* __restrict__ W2,
    const float* __restrict__ Wb1, const float* __restrict__ Wb2,
    const float* __restrict__ Wk,
    short* __restrict__ W1B, short* __restrict__ W2B,
    short* __restrict__ W1K, short* __restrict__ W2K,
    short* __restrict__ WkB,
    const float* __restrict__ ori, const float* __restrict__ Wo1,
    const float* __restrict__ bo1, const float* __restrict__ Wo2,
    const float* __restrict__ bo2, const float* __restrict__ Wf,
    float* __restrict__ fkb,
    const float* __restrict__ f, const float* __restrict__ We,
    float* __restrict__ xe)
{
    int b = blockIdx.x;
    if (b < 4) {
        if (b < 2) {
            int l2 = b;
            const float* w1 = W1 + l2*16384; short* w1p = W1B + l2*16384;
            const float* w2 = W2 + l2*16384; short* w2p = W2B + l2*16384;
            // W1B': frag f = nt*2+kc (nt 0..15, kc 0..1); lane l; elem j
            for (int i = threadIdx.x; i < 16384; i += 256) {
                int idx = i >> 3, j = i & 7;
                int fr = idx >> 6, l = idx & 63;
                int nt = fr >> 1, kc = fr & 1;
                int t = nt*16 + (l & 15);
                int k = kc*32 + (l >> 4)*8 + j;
                w1p[i] = f2bf(w1[k*256 + t]);
            }
            // W2B': frag f = (nc*2+ph)*4+kc2; lane l; elem j
            for (int i = threadIdx.x; i < 16384; i += 256) {
                int idx = i >> 3, j = i & 7;
                int fr = idx >> 6, l = idx & 63;
                int nc = fr >> 3, ph = (fr >> 2) & 1, kc2 = fr & 3;
                int c = nc*16 + (l & 15);
                int t = ph*128 + kc2*32 + (l >> 4)*8 + j;
                w2p[i] = f2bf(w2[t*64 + c]);
            }
        } else if (b == 2) {
            // W1K': frag nt (0..3); lane l; elem j   (K=32, zero-pad k>=30)
            for (int i = threadIdx.x; i < 2048; i += 256) {
                int idx = i >> 3, j = i & 7;
                int nt = idx >> 6, l = idx & 63;
                int t = nt*16 + (l & 15);
                int k = (l >> 4)*8 + j;
                W1K[i] = (k < 30) ? f2bf(Wb1[k*64 + t]) : (short)0;
            }
            // W2K': frag f = nt*2+kc; lane l; elem j
            for (int i = threadIdx.x; i < 4096; i += 256) {
                int idx = i >> 3, j = i & 7;
                int fr = idx >> 6, l = idx & 63;
                int nt = fr >> 1, kc = fr & 1;
                int c = nt*16 + (l & 15);
                int k = kc*32 + (l >> 4)*8 + j;
                W2K[i] = f2bf(Wb2[k*64 + c]);
            }
        } else {
            // Wk': per layer, frag f = nt*2+kc; lane l; elem j
            for (int i = threadIdx.x; i < 8192; i += 256) {
                int lay = i >> 12, rem = i & 4095;
                int idx = rem >> 3, j = rem & 7;
                int fr = idx >> 6, l = idx & 63;
                int nt = fr >> 1, kc = fr & 1;
                int c = nt*16 + (l & 15);
                int k = kc*32 + (l >> 4)*8 + j;
                WkB[i] = f2bf(Wk[lay*4096 + k*64 + c]);
            }
        }
    } else if (b < 40) {
        __shared__ float sh[4][64];
        __shared__ float skb[4][64];
        int w = threadIdx.x >> 6, lane = threadIdx.x & 63;
        int p = (b - 4)*4 + w;                      // 0..143
        int i = p / 12, j = p % 12;
        float s = ori[3*i]*ori[3*j] + ori[3*i+1]*ori[3*j+1] + ori[3*i+2]*ori[3*j+2];
        float p1 = s, p2 = s*s, p3 = p2*s, p4 = p3*s;
        float acc = bo1[lane] + p1*Wo1[lane] + p2*Wo1[64+lane] + p3*Wo1[128+lane] + p4*Wo1[192+lane];
        sh[w][lane] = gelu_exact(acc);
        __builtin_amdgcn_wave_barrier();
        float acc2 = bo2[lane];
        #pragma unroll
        for (int k = 0; k < 64; k++) acc2 += sh[w][k] * Wo2[k*64 + lane];
        skb[w][lane] = gelu_exact(acc2);
        __builtin_amdgcn_wave_barrier();
        for (int l = 0; l < 2; l++) {
            float a = 0.f;
            #pragma unroll
            for (int k = 0; k < 64; k++) a += skb[w][k] * Wf[l*4096 + k*64 + lane];
            fkb[l*9216 + i*768 + j*64 + lane] = a;
        }
    } else {
        int v = (b - 40)*4 + (threadIdx.x >> 6);
        int lane = threadIdx.x & 63;
        if (v >= N_NODES) return;
        float acc = 0.f;
        #pragma unroll
        for (int k = 0; k < 16; k++) acc += f[v*16 + k] * We[k*64 + lane];
        xe[v*64 + lane] = acc;
    }
}

// ---------------------------------------------------------------------------
// K3 (v16): kb MLP — M=32 rows/wave, per-lane-frag weights.
//  * Phase A: ONE thread per row (round-5 form — the 2-thread/row split of
//    round 8 DUPLICATED the 28-mult feature chain and cost 4%; at 8 blocks/CU
//    idle threads are free, extra instructions are not).
//  * LDS row strides padded 40->44 and 72->76 shorts (bank conflicts
//    3.12M -> 480K cyc/dispatch, verified round 8).
//  LDS: 4 waves * 2496 shorts = 19968 B -> 8 blocks/CU.
// ---------------------------------------------------------------------------
#define KB_WREG32 2496   // 32 rows * 76 shorts + 32 env floats (64 shorts)
__global__ __launch_bounds__(256, 8) void kb_mfma(
    const float* __restrict__ pos, const float* __restrict__ ori,
    const short* __restrict__ W1K, const float* __restrict__ bb1,
    const short* __restrict__ W2K, const float* __restrict__ bb2,
    const short* __restrict__ WkA, __hip_bfloat16* __restrict__ akbA,
    const short* __restrict__ WkB2, __hip_bfloat16* __restrict__ akbB,
    int dual, const int* __restrict__ srcOf, const int* __restrict__ dstOf)
{
    __shared__ short sU[4*KB_WREG32];

    int tid = threadIdx.x;
    int w = tid >> 6, l = tid & 63;
    short* reg  = sU + w*KB_WREG32;
    float* envp = (float*)(reg + 32*76);
    int blockRow = blockIdx.x * 128;

    // ---- Phase A: threads 0-127 -> one row each (cross-wave LDS write) ----
    if (tid < 128) {
        int row = blockRow + tid;
        int j = row / 12, o = row - j*12;
        int sn = srcOf[j], dn = dstOf[j];
        float rx = pos[sn*3+0] - pos[dn*3+0];
        float ry = pos[sn*3+1] - pos[dn*3+1];
        float rz = pos[sn*3+2] - pos[dn*3+2];
        float d  = sqrtf(rx*rx + ry*ry + rz*rz);
        float u2 = d*d, u4 = u2*u2, u6 = u4*u2;
        float env = (d < 1.0f) ? (1.0f - 28.0f*u6 + 48.0f*u6*d - 21.0f*u6*u2) : 0.0f;

        int wv = tid >> 5;           // owning wave
        int lr = tid & 31;           // local row within wave
        short* wreg = sU + wv*KB_WREG32;
        float* wenv = (float*)(wreg + 32*76);
        wenv[lr] = env;

        float ox = ori[3*o], oy = ori[3*o+1], oz = ori[3*o+2];
        float a  = rx*ox + ry*oy + rz*oz;
        float qx = rx - a*ox, qy = ry - a*oy, qz = rz - a*oz;
        float b  = sqrtf(qx*qx + qy*qy + qz*qz);

        float fv[32];
        fv[0] = a; fv[1] = b;
        fv[2] = a*a; fv[3] = a*b; fv[4] = b*a; fv[5] = b*b;
        #pragma unroll
        for (int i = 0; i < 4; i++) { fv[6+2*i] = fv[2+i]*a; fv[7+2*i] = fv[2+i]*b; }
        #pragma unroll
        for (int i = 0; i < 8; i++) { fv[14+2*i] = fv[6+i]*a; fv[15+2*i] = fv[6+i]*b; }
        fv[30] = 0.f; fv[31] = 0.f;

        short* dst = wreg + lr*44;
        #pragma unroll
        for (int blk = 0; blk < 4; blk++) {
            union { short s[8]; int4 v4; } u;
            #pragma unroll
            for (int jj = 0; jj < 8; jj++) u.s[jj] = f2bf(fv[blk*8 + jj]);
            *(int4*)(dst + blk*8) = u.v4;
        }
    }
    __syncthreads();

    int m16 = l & 15, q = l >> 4;

    bfrag a1[2];
    #pragma unroll
    for (int mt = 0; mt < 2; mt++)
        a1[mt] = *(const bfrag*)(reg + (mt*16 + m16)*44 + q*8);
    __builtin_amdgcn_wave_barrier();

    // ---- FFN1: K=32, swapped -> lane holds c = nt*16+q*4+r of row mt*16+m16
    #pragma unroll
    for (int nt = 0; nt < 4; nt++) {
        bfrag bb = *(const bfrag*)(W1K + (nt*64 + l)*8);
        f32x4 b4 = *(const f32x4*)(bb1 + nt*16 + q*4);
        #pragma unroll
        for (int mt = 0; mt < 2; mt++) {
            f32x4 acc = (f32x4){0.f,0.f,0.f,0.f};
            acc = __builtin_amdgcn_mfma_f32_16x16x32_bf16(bb, a1[mt], acc, 0, 0, 0);
            int2 pk = pack4(gelu_f(acc[0] + b4[0]), gelu_f(acc[1] + b4[1]),
                            gelu_f(acc[2] + b4[2]), gelu_f(acc[3] + b4[3]));
            *(int2*)(reg + (mt*16 + m16)*76 + nt*16 + q*4) = pk;
        }
    }
    __builtin_amdgcn_wave_barrier();

    // ---- FFN2: K=64 -> kb back into LDS (same swapped layout) ----
    bfrag a2[2][2];
    #pragma unroll
    for (int mt = 0; mt < 2; mt++)
        #pragma unroll
        for (int kc = 0; kc < 2; kc++)
            a2[mt][kc] = *(const bfrag*)(reg + (mt*16 + m16)*76 + kc*32 + q*8);
    __builtin_amdgcn_wave_barrier();

    #pragma unroll
    for (int nt = 0; nt < 4; nt++) {
        f32x4 acc[2];
        #pragma unroll
        for (int mt = 0; mt < 2; mt++) acc[mt] = (f32x4){0.f,0.f,0.f,0.f};
        #pragma unroll
        for (int kc = 0; kc < 2; kc++) {
            bfrag bb = *(const bfrag*)(W2K + ((nt*2 + kc)*64 + l)*8);
            #pragma unroll
            for (int mt = 0; mt < 2; mt++)
                acc[mt] = __builtin_amdgcn_mfma_f32_16x16x32_bf16(bb, a2[mt][kc], acc[mt], 0, 0, 0);
        }
        f32x4 b4 = *(const f32x4*)(bb2 + nt*16 + q*4);
        #pragma unroll
        for (int mt = 0; mt < 2; mt++) {
            float env = envp[mt*16 + m16];
            int2 pk = pack4(gelu_f(acc[mt][0] + b4[0]) * env,
                            gelu_f(acc[mt][1] + b4[1]) * env,
                            gelu_f(acc[mt][2] + b4[2]) * env,
                            gelu_f(acc[mt][3] + b4[3]) * env);
            *(int2*)(reg + (mt*16 + m16)*76 + nt*16 + q*4) = pk;
        }
    }
    __builtin_amdgcn_wave_barrier();

    // ---- akb GEMMs, swapped -> direct 8B coalesced-chunk stores ----
    bfrag a3[2][2];
    #pragma unroll
    for (int mt = 0; mt < 2; mt++)
        #pragma unroll
        for (int kc = 0; kc < 2; kc++)
            a3[mt][kc] = *(const bfrag*)(reg + (mt*16 + m16)*76 + kc*32 + q*8);

    #pragma unroll
    for (int nt = 0; nt < 4; nt++) {
        f32x4 acc[2];
        #pragma unroll
        for (int mt = 0; mt < 2; mt++) acc[mt] = (f32x4){0.f,0.f,0.f,0.f};
        #pragma unroll
        for (int kc = 0; kc < 2; kc++) {
            bfrag bb = *(const bfrag*)(WkA + ((nt*2 + kc)*64 + l)*8);
            #pragma unroll
            for (int mt = 0; mt < 2; mt++)
                acc[mt] = __builtin_amdgcn_mfma_f32_16x16x32_bf16(bb, a3[mt][kc], acc[mt], 0, 0, 0);
        }
        #pragma unroll
        for (int mt = 0; mt < 2; mt++) {
            int R = blockRow + w*32 + mt*16 + m16;
            int2 pk = pack4(acc[mt][0], acc[mt][1], acc[mt][2], acc[mt][3]);
            *(int2*)((short*)akbA + (size_t)R*64 + nt*16 + q*4) = pk;
        }
    }
    if (dual) {
        #pragma unroll
        for (int nt = 0; nt < 4; nt++) {
            f32x4 acc[2];
            #pragma unroll
            for (int mt = 0; mt < 2; mt++) acc[mt] = (f32x4){0.f,0.f,0.f,0.f};
            #pragma unroll
            for (int kc = 0; kc < 2; kc++) {
                bfrag bb = *(const bfrag*)(WkB2 + ((nt*2 + kc)*64 + l)*8);
                #pragma unroll
                for (int mt = 0; mt < 2; mt++)
                    acc[mt] = __builtin_amdgcn_mfma_f32_16x16x32_bf16(bb, a3[mt][kc], acc[mt], 0, 0, 0);
            }
            #pragma unroll
            for (int mt = 0; mt < 2; mt++) {
                int R = blockRow + w*32 + mt*16 + m16;
                int2 pk = pack4(acc[mt][0], acc[mt][1], acc[mt][2], acc[mt][3]);
                *(int2*)((short*)akbB + (size_t)R*64 + nt*16 + q*4) = pk;
            }
        }
    }
}

// ---------------------------------------------------------------------------
// K4a: layer-0 CSR gather — 8-way unrolled, max-occupancy hint.
// ---------------------------------------------------------------------------
__global__ __launch_bounds__(256, 8) void gather0(
    const __hip_bfloat16* __restrict__ akb,
    const int* __restrict__ srcOf, const int* __restrict__ rp,
    const float* __restrict__ xe, __hip_bfloat16* __restrict__ x1)
{
    int w = threadIdx.x >> 6, lane = threadIdx.x & 63;
    int g = blockIdx.x*4 + w;
    int v = g / 12, o = g - v*12;
    int jb = rp[v], je = rp[v+1];
    float acc = 0.f;
    int j = jb;
    for (; j + 7 < je; j += 8) {
        float a[8], x[8];
        #pragma unroll
        for (int ii = 0; ii < 8; ii++)
            a[ii] = __bfloat162float(akb[(size_t)(j+ii)*768 + o*64 + lane]);
        #pragma unroll
        for (int ii = 0; ii < 8; ii++)
            x[ii] = xe[(size_t)srcOf[j+ii]*64 + lane];
        #pragma unroll
        for (int ii = 0; ii < 8; ii++) acc += a[ii]*x[ii];
    }
    for (; j < je; j++) {
        float a0 = __bfloat162float(akb[(size_t)j*768 + o*64 + lane]);
        acc += a0 * xe[(size_t)srcOf[j]*64 + lane];
    }
    x1[(size_t)v*768 + o*64 + lane] = __float2bfloat16(acc);
}

// ---------------------------------------------------------------------------
// K4b: layer-1 CSR gather — 8-way unrolled, max-occupancy hint.
// ---------------------------------------------------------------------------
__global__ __launch_bounds__(256, 8) void gather1(
    const __hip_bfloat16* __restrict__ akb,
    const int* __restrict__ srcOf, const int* __restrict__ rp,
    const __hip_bfloat16* __restrict__ x_in, __hip_bfloat16* __restrict__ x1)
{
    int w = threadIdx.x >> 6, lane = threadIdx.x & 63;
    int g = blockIdx.x*4 + w;
    int v = g / 12, o = g - v*12;
    int jb = rp[v], je = rp[v+1];
    float acc = 0.f;
    int j = jb;
    for (; j + 7 < je; j += 8) {
        float a[8], x[8];
        #pragma unroll
        for (int ii = 0; ii < 8; ii++)
            a[ii] = __bfloat162float(akb[(size_t)(j+ii)*768 + o*64 + lane]);
        #pragma unroll
        for (int ii = 0; ii < 8; ii++)
            x[ii] = __bfloat162float(x_in[(size_t)srcOf[j+ii]*768 + o*64 + lane]);
        #pragma unroll
        for (int ii = 0; ii < 8; ii++) acc += a[ii]*x[ii];
    }
    for (; j < je; j++) {
        float a0 = __bfloat162float(akb[(size_t)j*768 + o*64 + lane]);
        acc += a0 * __bfloat162float(x_in[(size_t)srcOf[j]*768 + o*64 + lane]);
    }
    x1[(size_t)v*768 + o*64 + lane] = __float2bfloat16(acc);
}

// ---------------------------------------------------------------------------
// K5 (v13): node kernel — round-5 form (546us run): (256,8),
// per-lane-frag weights, inline union f2bf stores (no pointer escape).
// ---------------------------------------------------------------------------
#define ND_WREG2 2176
__global__ __launch_bounds__(256, 8) void node_mfma(
    const short* __restrict__ x1, const float* __restrict__ fk,
    const float* __restrict__ conv_b, const float* __restrict__ ln_g,
    const float* __restrict__ ln_b,
    const short* __restrict__ W1B, const float* __restrict__ b1,
    const short* __restrict__ W2B, const float* __restrict__ pb2,
    const float* __restrict__ Wr, const float* __restrict__ br,
    const __hip_bfloat16* __restrict__ x_old, __hip_bfloat16* __restrict__ x_new,
    float* __restrict__ racc, int has_res, int write_x, int lay)
{
    __shared__ short sU[4*ND_WREG2];

    int tid = threadIdx.x;
    int w   = tid >> 6;
    int blockRow = blockIdx.x * 64;
    short* reg = sU + w*ND_WREG2;

    // ---- Phase A: conv + LN, quarter-row (16 cols) per thread ----
    {
        int rl = tid >> 2;
        int qt = tid & 3;
        int lr = rl - 16*w;
        int row = blockRow + rl;                 // grid exact: row < N_ROWS
        int v = row / 12, pp = row % 12;
        float h[16];
        #pragma unroll
        for (int k = 0; k < 16; k++) h[k] = 0.f;
        const short* xv = x1 + (size_t)v*768 + qt*16;
        const float* fp = fk + (size_t)pp*768 + qt*16;
        #pragma unroll
        for (int o = 0; o < 12; o++) {
            const int4*  xa = (const int4*)(xv + o*64);
            const float4* fa = (const float4*)(fp + o*64);
            #pragma unroll
            for (int k4 = 0; k4 < 2; k4++) {
                int4 xi = xa[k4];
                float4 f0 = fa[2*k4], f1 = fa[2*k4+1];
                h[8*k4+0] += bflo((unsigned)xi.x)*f0.x; h[8*k4+1] += bfhi((unsigned)xi.x)*f0.y;
                h[8*k4+2] += bflo((unsigned)xi.y)*f0.z; h[8*k4+3] += bfhi((unsigned)xi.y)*f0.w;
                h[8*k4+4] += bflo((unsigned)xi.z)*f1.x; h[8*k4+5] += bfhi((unsigned)xi.z)*f1.y;
                h[8*k4+6] += bflo((unsigned)xi.w)*f1.z; h[8*k4+7] += bfhi((unsigned)xi.w)*f1.w;
            }
        }
        const float inv12 = 1.0f/12.0f;
        float sum = 0.f;
        #pragma unroll
        for (int k = 0; k < 16; k++) { h[k] = h[k]*inv12 + conv_b[qt*16 + k]; sum += h[k]; }
        sum += __shfl_xor(sum, 1);
        sum += __shfl_xor(sum, 2);
        float mu = sum * (1.0f/64.0f);
        float var = 0.f;
        #pragma unroll
        for (int k = 0; k < 16; k++) { float xc = h[k] - mu; var += xc*xc; }
        var += __shfl_xor(var, 1);
        var += __shfl_xor(var, 2);
        float rstd = rsqrtf(var*(1.0f/64.0f) + 1e-5f);
        short* dst = reg + lr*72 + qt*16;
        #pragma unroll
        for (int blk = 0; blk < 2; blk++) {
            union { short s[8]; int4 v4; } u;
            #pragma unroll
            for (int jj = 0; jj < 8; jj++) {
                int k = blk*8 + jj, c = qt*16 + k;
                u.s[jj] = f2bf((h[k] - mu)*rstd*ln_g[c] + ln_b[c]);
            }
            *(int4*)(dst + blk*8) = u.v4;
        }
    }
    __builtin_amdgcn_wave_barrier();

    int l   = tid & 63;
    int m16 = l & 15, q = l >> 4;

    bfrag a1[2];
    #pragma unroll
    for (int kc = 0; kc < 2; kc++)
        a1[kc] = *(const bfrag*)(reg + m16*72 + kc*32 + q*8);
    __builtin_amdgcn_wave_barrier();

    f32x4 acc2[4];
    #pragma unroll
    for (int n = 0; n < 4; n++) acc2[n] = (f32x4){0.f, 0.f, 0.f, 0.f};

    for (int ph = 0; ph < 2; ph++) {
        // FFN1 swapped: lane holds c = nt*16+q*4+r of row m16
        for (int ntl = 0; ntl < 8; ntl++) {
            int nt = ph*8 + ntl;
            f32x4 c0 = (f32x4){0.f,0.f,0.f,0.f};
            #pragma unroll
            for (int kc = 0; kc < 2; kc++) {
                bfrag bb = *(const bfrag*)(W1B + ((nt*2 + kc)*64 + l)*8);
                c0 = __builtin_amdgcn_mfma_f32_16x16x32_bf16(bb, a1[kc], c0, 0, 0, 0);
            }
            f32x4 b4 = *(const f32x4*)(b1 + nt*16 + q*4);
            int2 pk = pack4(gelu_f(c0[0] + b4[0]), gelu_f(c0[1] + b4[1]),
                            gelu_f(c0[2] + b4[2]), gelu_f(c0[3] + b4[3]));
            *(int2*)(reg + m16*136 + ntl*16 + q*4) = pk;
        }
        __builtin_amdgcn_wave_barrier();
        for (int kc2 = 0; kc2 < 4; kc2++) {
            bfrag a2 = *(const bfrag*)(reg + m16*136 + kc2*32 + q*8);
            #pragma unroll
            for (int nc = 0; nc < 4; nc++) {
                bfrag bb = *(const bfrag*)(W2B + (((nc*2 + ph)*4 + kc2)*64 + l)*8);
                acc2[nc] = __builtin_amdgcn_mfma_f32_16x16x32_bf16(bb, a2, acc2[nc], 0, 0, 0);
            }
        }
        __builtin_amdgcn_wave_barrier();
    }

    // ---- Epilogue: lane owns row (blockRow + 16w + m16), cols nc*16+q*4..+3
    int row = blockRow + 16*w + m16;
    float q0 = 0.f, q1 = 0.f;
    #pragma unroll
    for (int nc = 0; nc < 4; nc++) {
        int cb = nc*16 + q*4;
        f32x4 pb4 = *(const f32x4*)(pb2 + cb);
        float vals[4];
        #pragma unroll
        for (int r = 0; r < 4; r++) vals[r] = acc2[nc][r] + pb4[r];
        if (has_res) {
            int2 xo = *(const int2*)((const short*)x_old + (size_t)row*64 + cb);
            vals[0] += bflo((unsigned)xo.x); vals[1] += bfhi((unsigned)xo.x);
            vals[2] += bflo((unsigned)xo.y); vals[3] += bfhi((unsigned)xo.y);
        }
        if (write_x) {
            int2 pk = pack4(vals[0], vals[1], vals[2], vals[3]);
            *(int2*)((short*)x_new + (size_t)row*64 + cb) = pk;
        }
        f32x4 wr0 = *(const f32x4*)(Wr + 2*cb);
        f32x4 wr1 = *(const f32x4*)(Wr + 2*cb + 4);
        q0 += vals[0]*wr0[0] + vals[1]*wr0[2] + vals[2]*wr1[0] + vals[3]*wr1[2];
        q1 += vals[0]*wr0[1] + vals[1]*wr0[3] + vals[2]*wr1[1] + vals[3]*wr1[3];
    }
    q0 += __shfl_xor(q0, 16); q0 += __shfl_xor(q0, 32);
    q1 += __shfl_xor(q1, 16); q1 += __shfl_xor(q1, 32);
    if (q == 0) {
        racc[(size_t)row*4 + lay*2 + 0] = q0 + br[0];
        racc[(size_t)row*4 + lay*2 + 1] = q1 + br[1];
    }
}

// ---------------------------------------------------------------------------
// K6 (v3): readout — layer-separated racc, two-stage reduction (unchanged)
// ---------------------------------------------------------------------------
__global__ __launch_bounds__(256) void final_kernel(
    const float* __restrict__ racc, const float* __restrict__ ori,
    const int* __restrict__ batch, float* __restrict__ out)
{
    __shared__ float sAcc[64];
    int tid = threadIdx.x;
    if (tid < 64) sAcc[tid] = 0.f;
    __syncthreads();

    int v = blockIdx.x*256 + tid;
    if (v < N_NODES) {
        float srs = 0.f, vx = 0.f, vy = 0.f, vz = 0.f;
        #pragma unroll
        for (int p = 0; p < 12; p++) {
            const float* rr = racc + (size_t)(v*12 + p)*4;
            float r0 = rr[0] + rr[2];
            float r1 = rr[1] + rr[3];
            srs += r0;
            vx += r1*ori[3*p]; vy += r1*ori[3*p+1]; vz += r1*ori[3*p+2];
        }
        const float sc = 1.0f/24.0f;
        int g = batch[v];
        atomicAdd(&sAcc[g],            srs*sc);
        atomicAdd(&sAcc[16 + g*3 + 0], vx*sc);
        atomicAdd(&sAcc[16 + g*3 + 1], vy*sc);
        atomicAdd(&sAcc[16 + g*3 + 2], vz*sc);
    }
    __syncthreads();
    if (tid < 64) atomicAdd(&out[tid], sAcc[tid]);
}

extern "C" void kernel_launch(void* const* d_in, const int* in_sizes, int n_in,
                              void* d_out, int out_size, void* d_ws, size_t ws_size,
                              hipStream_t stream) {
    const float* pos    = (const float*)d_in[0];
    const float* f      = (const float*)d_in[1];
    const float* ori    = (const float*)d_in[2];
    const int*   ei     = (const int*)  d_in[3];
    const int*   batch  = (const int*)  d_in[4];
    const float* Wb1    = (const float*)d_in[5];
    const float* bb1    = (const float*)d_in[6];
    const float* Wb2    = (const float*)d_in[7];
    const float* bb2    = (const float*)d_in[8];
    const float* Wo1    = (const float*)d_in[9];
    const float* bo1    = (const float*)d_in[10];
    const float* Wo2    = (const float*)d_in[11];
    const float* bo2    = (const float*)d_in[12];
    const float* We     = (const float*)d_in[13];
    const float* Wk     = (const float*)d_in[14];
    const float* Wf     = (const float*)d_in[15];
    const float* conv_b = (const float*)d_in[16];
    const float* ln_g   = (const float*)d_in[17];
    const float* ln_b   = (const float*)d_in[18];
    const float* W1     = (const float*)d_in[19];
    const float* b1     = (const float*)d_in[20];
    const float* W2     = (const float*)d_in[21];
    const float* b2     = (const float*)d_in[22];
    const float* Wr     = (const float*)d_in[23];
    const float* br     = (const float*)d_in[24];
    float* out = (float*)d_out;

    float* ws   = (float*)d_ws;
    float* xe   = ws;                               //   640,000 f32
    short* xs1b = (short*)(xe + 640000);            // 7,680,000 bf16
    short* x1b  = xs1b + 7680000;                   // 7,680,000 bf16
    float* racc = (float*)(x1b + 7680000);          //   480,000 f32 (layered)
    float* fkb  = racc + 480000;                    //    18,432
    short* w1b  = (short*)(fkb + 18432);            //    32,768 shorts
    short* w2b  = w1b + 32768;
    short* w1k  = w2b + 32768;
    short* w2k  = w1k + 2048;
    short* wkb  = w2k + 4096;
    int*   deg  = (int*)(wkb + 8192);               //    10,000 ints
    int*   rp   = deg + 10000;
    int*   wp   = rp  + 10001;
    int*   dstO = wp  + 10000;                      // dst node per sorted slot
    int*   srcOf= dstO+ 80000;
    int*   pad_ = srcOf + 80000;
    __hip_bfloat16* akbA = (__hip_bfloat16*)(pad_ + 3);   // 61,440,000 bf16 (~123 MB)
    __hip_bfloat16* akbB = akbA + 61440000;               // second buffer (full mode)

    size_t need_full = ((char*)(akbB + 61440000)) - ((char*)d_ws);
    int full = (ws_size >= need_full) ? 1 : 0;

    hipMemsetAsync(out,  0, 64*sizeof(float), stream);
    hipMemsetAsync(deg,  0, 10000*sizeof(int), stream);

    csr_count<<<313, 256, 0, stream>>>(ei, deg);
    csr_scan <<<1,   256, 0, stream>>>(deg, rp, wp);
    csr_fill <<<313, 256, 0, stream>>>(ei, wp, dstO, srcOf);

    setup_kernel<<<2540, 256, 0, stream>>>(W1, W2, Wb1, Wb2, Wk,
                                           w1b, w2b, w1k, w2k, wkb,
                                           ori, Wo1, bo1, Wo2, bo2, Wf, fkb,
                                           f, We, xe);

    if (full) {
        kb_mfma <<<7500, 256, 0, stream>>>(pos, ori, w1k, bb1, w2k, bb2,
                                           wkb, akbA, wkb + 4096, akbB, /*dual=*/1, srcOf, dstO);
        gather0 <<<30000,256, 0, stream>>>(akbA, srcOf, rp, xe, (__hip_bfloat16*)x1b);
        node_mfma<<<1875,256, 0, stream>>>(x1b, fkb, conv_b, ln_g, ln_b,
                                           w1b, b1, w2b, b2, Wr, br,
                                           (const __hip_bfloat16*)xs1b, (__hip_bfloat16*)xs1b,
                                           racc, /*res=*/0, /*write=*/1, /*lay=*/0);
        gather1 <<<30000,256, 0, stream>>>(akbB, srcOf, rp,
                                           (const __hip_bfloat16*)xs1b, (__hip_bfloat16*)x1b);
    } else {
        kb_mfma <<<7500, 256, 0, stream>>>(pos, ori, w1k, bb1, w2k, bb2,
                                           wkb, akbA, wkb, akbA, /*dual=*/0, srcOf, dstO);
        gather0 <<<30000,256, 0, stream>>>(akbA, srcOf, rp, xe, (__hip_bfloat16*)x1b);
        node_mfma<<<1875,256, 0, stream>>>(x1b, fkb, conv_b, ln_g, ln_b,
                                           w1b, b1, w2b, b2, Wr, br,
                                           (const __hip_bfloat16*)xs1b, (__hip_bfloat16*)xs1b,
                                           racc, /*res=*/0, /*write=*/1, /*lay=*/0);
        kb_mfma <<<7500, 256, 0, stream>>>(pos, ori, w1k, bb1, w2k, bb2,
                                           wkb + 4096, akbA, wkb + 4096, akbA, /*dual=*/0, srcOf, dstO);
        gather1 <<<30000,256, 0, stream>>>(akbA, srcOf, rp,
                                           (const __hip_bfloat16*)xs1b, (__hip_bfloat16*)x1b);
    }

    node_mfma   <<<1875, 256, 0, stream>>>(x1b, fkb + 9216, conv_b + 64, ln_g + 64, ln_b + 64,
                                           w1b + 16384, b1 + 256, w2b + 16384, b2 + 64,
                                           Wr + 128, br + 2,
                                           (const __hip_bfloat16*)xs1b, (__hip_bfloat16*)xs1b,
                                           racc, /*res=*/1, /*write=*/0, /*lay=*/1);

    final_kernel<<<40,   256, 0, stream>>>(racc, ori, batch, out);
}

// Round 10
// 544.685 us; speedup vs baseline: 1.0402x; 1.0402x over previous
//
#include <hip/hip_runtime.h>
#include <hip/hip_bf16.h>
#include <math.h>

#define N_NODES 10000
#define N_EDGES 80000
#define N_ORI   12
#define N_ROWS  (N_NODES * N_ORI)

typedef __attribute__((ext_vector_type(8))) short bfrag;   // 8 bf16 = 4 VGPRs
typedef __attribute__((ext_vector_type(4))) float f32x4;

// fast gelu (tanh-approx, overflow-safe); |err| < ~3e-3 < bf16 ulp downstream.
// __expf form is PROVEN FASTEST: __expf = v_mul+v_exp (fast intrinsic);
// exp2f (round 9) lowers to ocml precise path with denormal fixup (+3 VALU
// per call x 64 calls/thread -> +8us on kb). Keep __expf.
__device__ __forceinline__ float gelu_f(float x) {
    float u = 1.5957691216057308f * x * (1.0f + 0.044715f * x * x);
    float e = __expf(-u);
    return x * __builtin_amdgcn_rcpf(1.0f + e);
}
// exact gelu for the tiny f32-precision ori path
__device__ __forceinline__ float gelu_exact(float x) {
    return 0.5f * x * (1.0f + erff(x * 0.70710678118654752440f));
}
// NOTE: keep the compiler's __float2bfloat16 path. Inline-asm cvt_pk failed
// correctness (round 6, absmax 468). NEVER pass local arrays by pointer into
// pack helpers: round 7 showed that sends the array to scratch (+120MB HBM
// traffic in node_mfma, rule #20). Use inline union loops with constant idx.
__device__ __forceinline__ short f2bf(float x) {
    __hip_bfloat16 h = __float2bfloat16(x);
    return *reinterpret_cast<short*>(&h);
}
__device__ __forceinline__ float bflo(unsigned u) { return __uint_as_float(u << 16); }
__device__ __forceinline__ float bfhi(unsigned u) { return __uint_as_float(u & 0xffff0000u); }

// pack 4 f32 (by value) -> 4 bf16 in memory order
__device__ __forceinline__ int2 pack4(float a, float b, float c, float d) {
    union { short s[4]; int2 v; } u;
    u.s[0] = f2bf(a); u.s[1] = f2bf(b); u.s[2] = f2bf(c); u.s[3] = f2bf(d);
    return u.v;
}

// ---------------------------------------------------------------------------
// CSR build (dst-sorted edge list for gathers)
// ---------------------------------------------------------------------------
__global__ __launch_bounds__(256) void csr_count(
    const int* __restrict__ ei, int* __restrict__ deg)
{
    int e = blockIdx.x*256 + threadIdx.x;
    if (e < N_EDGES) atomicAdd(&deg[ei[N_EDGES + e]], 1);
}

__global__ __launch_bounds__(256) void csr_scan(
    const int* __restrict__ deg, int* __restrict__ rp, int* __restrict__ wp)
{
    __shared__ int part[256];
    __shared__ int sbase[257];
    int t = threadIdx.x;
    int cs = t*40;
    int sum = 0;
    for (int i = 0; i < 40; i++) { int idx = cs+i; if (idx < N_NODES) sum += deg[idx]; }
    part[t] = sum;
    __syncthreads();
    if (t == 0) {
        int run = 0;
        for (int i = 0; i < 256; i++) { sbase[i] = run; run += part[i]; }
        sbase[256] = run;
    }
    __syncthreads();
    int run = sbase[t];
    for (int i = 0; i < 40; i++) {
        int idx = cs+i;
        if (idx < N_NODES) { rp[idx] = run; wp[idx] = run; run += deg[idx]; }
    }
    if (t == 0) rp[N_NODES] = sbase[256];
}

__global__ __launch_bounds__(256) void csr_fill(
    const int* __restrict__ ei, int* __restrict__ wp,
    int* __restrict__ dstOf, int* __restrict__ srcOf)
{
    int e = blockIdx.x*256 + threadIdx.x;
    if (e >= N_EDGES) return;
    int dn = ei[N_EDGES + e];
    int j = atomicAdd(&wp[dn], 1);
    dstOf[j] = dn;
    srcOf[j] = ei[e];
}

// ---------------------------------------------------------------------------
// K0 (fused setup): blocks 0-3 weight prep; 4-39 ori MLP+fk; 40-2539 embed.
// Weight buffers stored in PER-LANE FRAGMENT ORDER: W'[frag][lane][8] so MFMA
// operand loads are contiguous 1KB per wave instruction.
// ---------------------------------------------------------------------------
__global__ __launch_bounds__(256) void setup_kernel(
    const float* __restrict__ W1, const float* __restrict__ W2,
    const float* __restrict__ Wb1, const float* __restrict__ Wb2,
    const float* __restrict__ Wk,
    short* __restrict__ W1B, short* __restrict__ W2B,
    short* __restrict__ W1K, short* __restrict__ W2K,
    short* __restrict__ WkB,
    const float* __restrict__ ori, const float* __restrict__ Wo1,
    const float* __restrict__ bo1, const float* __restrict__ Wo2,
    const float* __restrict__ bo2, const float* __restrict__ Wf,
    float* __restrict__ fkb,
    const float* __restrict__ f, const float* __restrict__ We,
    float* __restrict__ xe)
{
    int b = blockIdx.x;
    if (b < 4) {
        if (b < 2) {
            int l2 = b;
            const float* w1 = W1 + l2*16384; short* w1p = W1B + l2*16384;
            const float* w2 = W2 + l2*16384; short* w2p = W2B + l2*16384;
            // W1B': frag f = nt*2+kc (nt 0..15, kc 0..1); lane l; elem j
            for (int i = threadIdx.x; i < 16384; i += 256) {
                int idx = i >> 3, j = i & 7;
                int fr = idx >> 6, l = idx & 63;
                int nt = fr >> 1, kc = fr & 1;
                int t = nt*16 + (l & 15);
                int k = kc*32 + (l >> 4)*8 + j;
                w1p[i] = f2bf(w1[k*256 + t]);
            }
            // W2B': frag f = (nc*2+ph)*4+kc2; lane l; elem j
            for (int i = threadIdx.x; i < 16384; i += 256) {
                int idx = i >> 3, j = i & 7;
                int fr = idx >> 6, l = idx & 63;
                int nc = fr >> 3, ph = (fr >> 2) & 1, kc2 = fr & 3;
                int c = nc*16 + (l & 15);
                int t = ph*128 + kc2*32 + (l >> 4)*8 + j;
                w2p[i] = f2bf(w2[t*64 + c]);
            }
        } else if (b == 2) {
            // W1K': frag nt (0..3); lane l; elem j   (K=32, zero-pad k>=30)
            for (int i = threadIdx.x; i < 2048; i += 256) {
                int idx = i >> 3, j = i & 7;
                int nt = idx >> 6, l = idx & 63;
                int t = nt*16 + (l & 15);
                int k = (l >> 4)*8 + j;
                W1K[i] = (k < 30) ? f2bf(Wb1[k*64 + t]) : (short)0;
            }
            // W2K': frag f = nt*2+kc; lane l; elem j
            for (int i = threadIdx.x; i < 4096; i += 256) {
                int idx = i >> 3, j = i & 7;
                int fr = idx >> 6, l = idx & 63;
                int nt = fr >> 1, kc = fr & 1;
                int c = nt*16 + (l & 15);
                int k = kc*32 + (l >> 4)*8 + j;
                W2K[i] = f2bf(Wb2[k*64 + c]);
            }
        } else {
            // Wk': per layer, frag f = nt*2+kc; lane l; elem j
            for (int i = threadIdx.x; i < 8192; i += 256) {
                int lay = i >> 12, rem = i & 4095;
                int idx = rem >> 3, j = rem & 7;
                int fr = idx >> 6, l = idx & 63;
                int nt = fr >> 1, kc = fr & 1;
                int c = nt*16 + (l & 15);
                int k = kc*32 + (l >> 4)*8 + j;
                WkB[i] = f2bf(Wk[lay*4096 + k*64 + c]);
            }
        }
    } else if (b < 40) {
        __shared__ float sh[4][64];
        __shared__ float skb[4][64];
        int w = threadIdx.x >> 6, lane = threadIdx.x & 63;
        int p = (b - 4)*4 + w;                      // 0..143
        int i = p / 12, j = p % 12;
        float s = ori[3*i]*ori[3*j] + ori[3*i+1]*ori[3*j+1] + ori[3*i+2]*ori[3*j+2];
        float p1 = s, p2 = s*s, p3 = p2*s, p4 = p3*s;
        float acc = bo1[lane] + p1*Wo1[lane] + p2*Wo1[64+lane] + p3*Wo1[128+lane] + p4*Wo1[192+lane];
        sh[w][lane] = gelu_exact(acc);
        __builtin_amdgcn_wave_barrier();
        float acc2 = bo2[lane];
        #pragma unroll
        for (int k = 0; k < 64; k++) acc2 += sh[w][k] * Wo2[k*64 + lane];
        skb[w][lane] = gelu_exact(acc2);
        __builtin_amdgcn_wave_barrier();
        for (int l = 0; l < 2; l++) {
            float a = 0.f;
            #pragma unroll
            for (int k = 0; k < 64; k++) a += skb[w][k] * Wf[l*4096 + k*64 + lane];
            fkb[l*9216 + i*768 + j*64 + lane] = a;
        }
    } else {
        int v = (b - 40)*4 + (threadIdx.x >> 6);
        int lane = threadIdx.x & 63;
        if (v >= N_NODES) return;
        float acc = 0.f;
        #pragma unroll
        for (int k = 0; k < 16; k++) acc += f[v*16 + k] * We[k*64 + lane];
        xe[v*64 + lane] = acc;
    }
}

// ---------------------------------------------------------------------------
// K3 (v17): kb MLP — M=32 rows/wave, per-lane-frag weights.
//  * Phase A: ONE thread per row (extra threads idle are free at 8 blk/CU;
//    round-8's 2t/row split duplicated the feature chain, -4%).
//  * LDS row strides padded 40->44 and 72->76 shorts: SQ_LDS_BANK_CONFLICT
//    = 0 (verified round 9).
//  * gelu via __expf (round-9's exp2f = ocml precise path, +3 VALU/call).
//  LDS: 4 waves * 2496 shorts = 19968 B -> 8 blocks/CU.
// ---------------------------------------------------------------------------
#define KB_WREG32 2496   // 32 rows * 76 shorts + 32 env floats (64 shorts)
__global__ __launch_bounds__(256, 8) void kb_mfma(
    const float* __restrict__ pos, const float* __restrict__ ori,
    const short* __restrict__ W1K, const float* __restrict__ bb1,
    const short* __restrict__ W2K, const float* __restrict__ bb2,
    const short* __restrict__ WkA, __hip_bfloat16* __restrict__ akbA,
    const short* __restrict__ WkB2, __hip_bfloat16* __restrict__ akbB,
    int dual, const int* __restrict__ srcOf, const int* __restrict__ dstOf)
{
    __shared__ short sU[4*KB_WREG32];

    int tid = threadIdx.x;
    int w = tid >> 6, l = tid & 63;
    short* reg  = sU + w*KB_WREG32;
    float* envp = (float*)(reg + 32*76);
    int blockRow = blockIdx.x * 128;

    // ---- Phase A: threads 0-127 -> one row each (cross-wave LDS write) ----
    if (tid < 128) {
        int row = blockRow + tid;
        int j = row / 12, o = row - j*12;
        int sn = srcOf[j], dn = dstOf[j];
        float rx = pos[sn*3+0] - pos[dn*3+0];
        float ry = pos[sn*3+1] - pos[dn*3+1];
        float rz = pos[sn*3+2] - pos[dn*3+2];
        float d  = sqrtf(rx*rx + ry*ry + rz*rz);
        float u2 = d*d, u4 = u2*u2, u6 = u4*u2;
        float env = (d < 1.0f) ? (1.0f - 28.0f*u6 + 48.0f*u6*d - 21.0f*u6*u2) : 0.0f;

        int wv = tid >> 5;           // owning wave
        int lr = tid & 31;           // local row within wave
        short* wreg = sU + wv*KB_WREG32;
        float* wenv = (float*)(wreg + 32*76);
        wenv[lr] = env;

        float ox = ori[3*o], oy = ori[3*o+1], oz = ori[3*o+2];
        float a  = rx*ox + ry*oy + rz*oz;
        float qx = rx - a*ox, qy = ry - a*oy, qz = rz - a*oz;
        float b  = sqrtf(qx*qx + qy*qy + qz*qz);

        float fv[32];
        fv[0] = a; fv[1] = b;
        fv[2] = a*a; fv[3] = a*b; fv[4] = b*a; fv[5] = b*b;
        #pragma unroll
        for (int i = 0; i < 4; i++) { fv[6+2*i] = fv[2+i]*a; fv[7+2*i] = fv[2+i]*b; }
        #pragma unroll
        for (int i = 0; i < 8; i++) { fv[14+2*i] = fv[6+i]*a; fv[15+2*i] = fv[6+i]*b; }
        fv[30] = 0.f; fv[31] = 0.f;

        short* dst = wreg + lr*44;
        #pragma unroll
        for (int blk = 0; blk < 4; blk++) {
            union { short s[8]; int4 v4; } u;
            #pragma unroll
            for (int jj = 0; jj < 8; jj++) u.s[jj] = f2bf(fv[blk*8 + jj]);
            *(int4*)(dst + blk*8) = u.v4;
        }
    }
    __syncthreads();

    int m16 = l & 15, q = l >> 4;

    bfrag a1[2];
    #pragma unroll
    for (int mt = 0; mt < 2; mt++)
        a1[mt] = *(const bfrag*)(reg + (mt*16 + m16)*44 + q*8);
    __builtin_amdgcn_wave_barrier();

    // ---- FFN1: K=32, swapped -> lane holds c = nt*16+q*4+r of row mt*16+m16
    #pragma unroll
    for (int nt = 0; nt < 4; nt++) {
        bfrag bb = *(const bfrag*)(W1K + (nt*64 + l)*8);
        f32x4 b4 = *(const f32x4*)(bb1 + nt*16 + q*4);
        #pragma unroll
        for (int mt = 0; mt < 2; mt++) {
            f32x4 acc = (f32x4){0.f,0.f,0.f,0.f};
            acc = __builtin_amdgcn_mfma_f32_16x16x32_bf16(bb, a1[mt], acc, 0, 0, 0);
            int2 pk = pack4(gelu_f(acc[0] + b4[0]), gelu_f(acc[1] + b4[1]),
                            gelu_f(acc[2] + b4[2]), gelu_f(acc[3] + b4[3]));
            *(int2*)(reg + (mt*16 + m16)*76 + nt*16 + q*4) = pk;
        }
    }
    __builtin_amdgcn_wave_barrier();

    // ---- FFN2: K=64 -> kb back into LDS (same swapped layout) ----
    bfrag a2[2][2];
    #pragma unroll
    for (int mt = 0; mt < 2; mt++)
        #pragma unroll
        for (int kc = 0; kc < 2; kc++)
            a2[mt][kc] = *(const bfrag*)(reg + (mt*16 + m16)*76 + kc*32 + q*8);
    __builtin_amdgcn_wave_barrier();

    #pragma unroll
    for (int nt = 0; nt < 4; nt++) {
        f32x4 acc[2];
        #pragma unroll
        for (int mt = 0; mt < 2; mt++) acc[mt] = (f32x4){0.f,0.f,0.f,0.f};
        #pragma unroll
        for (int kc = 0; kc < 2; kc++) {
            bfrag bb = *(const bfrag*)(W2K + ((nt*2 + kc)*64 + l)*8);
            #pragma unroll
            for (int mt = 0; mt < 2; mt++)
                acc[mt] = __builtin_amdgcn_mfma_f32_16x16x32_bf16(bb, a2[mt][kc], acc[mt], 0, 0, 0);
        }
        f32x4 b4 = *(const f32x4*)(bb2 + nt*16 + q*4);
        #pragma unroll
        for (int mt = 0; mt < 2; mt++) {
            float env = envp[mt*16 + m16];
            int2 pk = pack4(gelu_f(acc[mt][0] + b4[0]) * env,
                            gelu_f(acc[mt][1] + b4[1]) * env,
                            gelu_f(acc[mt][2] + b4[2]) * env,
                            gelu_f(acc[mt][3] + b4[3]) * env);
            *(int2*)(reg + (mt*16 + m16)*76 + nt*16 + q*4) = pk;
        }
    }
    __builtin_amdgcn_wave_barrier();

    // ---- akb GEMMs, swapped -> direct 8B coalesced-chunk stores ----
    bfrag a3[2][2];
    #pragma unroll
    for (int mt = 0; mt < 2; mt++)
        #pragma unroll
        for (int kc = 0; kc < 2; kc++)
            a3[mt][kc] = *(const bfrag*)(reg + (mt*16 + m16)*76 + kc*32 + q*8);

    #pragma unroll
    for (int nt = 0; nt < 4; nt++) {
        f32x4 acc[2];
        #pragma unroll
        for (int mt = 0; mt < 2; mt++) acc[mt] = (f32x4){0.f,0.f,0.f,0.f};
        #pragma unroll
        for (int kc = 0; kc < 2; kc++) {
            bfrag bb = *(const bfrag*)(WkA + ((nt*2 + kc)*64 + l)*8);
            #pragma unroll
            for (int mt = 0; mt < 2; mt++)
                acc[mt] = __builtin_amdgcn_mfma_f32_16x16x32_bf16(bb, a3[mt][kc], acc[mt], 0, 0, 0);
        }
        #pragma unroll
        for (int mt = 0; mt < 2; mt++) {
            int R = blockRow + w*32 + mt*16 + m16;
            int2 pk = pack4(acc[mt][0], acc[mt][1], acc[mt][2], acc[mt][3]);
            *(int2*)((short*)akbA + (size_t)R*64 + nt*16 + q*4) = pk;
        }
    }
    if (dual) {
        #pragma unroll
        for (int nt = 0; nt < 4; nt++) {
            f32x4 acc[2];
            #pragma unroll
            for (int mt = 0; mt < 2; mt++) acc[mt] = (f32x4){0.f,0.f,0.f,0.f};
            #pragma unroll
            for (int kc = 0; kc < 2; kc++) {
                bfrag bb = *(const bfrag*)(WkB2 + ((nt*2 + kc)*64 + l)*8);
                #pragma unroll
                for (int mt = 0; mt < 2; mt++)
                    acc[mt] = __builtin_amdgcn_mfma_f32_16x16x32_bf16(bb, a3[mt][kc], acc[mt], 0, 0, 0);
            }
            #pragma unroll
            for (int mt = 0; mt < 2; mt++) {
                int R = blockRow + w*32 + mt*16 + m16;
                int2 pk = pack4(acc[mt][0], acc[mt][1], acc[mt][2], acc[mt][3]);
                *(int2*)((short*)akbB + (size_t)R*64 + nt*16 + q*4) = pk;
            }
        }
    }
}

// ---------------------------------------------------------------------------
// K4a: layer-0 CSR gather — 8-way unrolled, max-occupancy hint.
// ---------------------------------------------------------------------------
__global__ __launch_bounds__(256, 8) void gather0(
    const __hip_bfloat16* __restrict__ akb,
    const int* __restrict__ srcOf, const int* __restrict__ rp,
    const float* __restrict__ xe, __hip_bfloat16* __restrict__ x1)
{
    int w = threadIdx.x >> 6, lane = threadIdx.x & 63;
    int g = blockIdx.x*4 + w;
    int v = g / 12, o = g - v*12;
    int jb = rp[v], je = rp[v+1];
    float acc = 0.f;
    int j = jb;
    for (; j + 7 < je; j += 8) {
        float a[8], x[8];
        #pragma unroll
        for (int ii = 0; ii < 8; ii++)
            a[ii] = __bfloat162float(akb[(size_t)(j+ii)*768 + o*64 + lane]);
        #pragma unroll
        for (int ii = 0; ii < 8; ii++)
            x[ii] = xe[(size_t)srcOf[j+ii]*64 + lane];
        #pragma unroll
        for (int ii = 0; ii < 8; ii++) acc += a[ii]*x[ii];
    }
    for (; j < je; j++) {
        float a0 = __bfloat162float(akb[(size_t)j*768 + o*64 + lane]);
        acc += a0 * xe[(size_t)srcOf[j]*64 + lane];
    }
    x1[(size_t)v*768 + o*64 + lane] = __float2bfloat16(acc);
}

// ---------------------------------------------------------------------------
// K4b: layer-1 CSR gather — 8-way unrolled, max-occupancy hint.
// ---------------------------------------------------------------------------
__global__ __launch_bounds__(256, 8) void gather1(
    const __hip_bfloat16* __restrict__ akb,
    const int* __restrict__ srcOf, const int* __restrict__ rp,
    const __hip_bfloat16* __restrict__ x_in, __hip_bfloat16* __restrict__ x1)
{
    int w = threadIdx.x >> 6, lane = threadIdx.x & 63;
    int g = blockIdx.x*4 + w;
    int v = g / 12, o = g - v*12;
    int jb = rp[v], je = rp[v+1];
    float acc = 0.f;
    int j = jb;
    for (; j + 7 < je; j += 8) {
        float a[8], x[8];
        #pragma unroll
        for (int ii = 0; ii < 8; ii++)
            a[ii] = __bfloat162float(akb[(size_t)(j+ii)*768 + o*64 + lane]);
        #pragma unroll
        for (int ii = 0; ii < 8; ii++)
            x[ii] = __bfloat162float(x_in[(size_t)srcOf[j+ii]*768 + o*64 + lane]);
        #pragma unroll
        for (int ii = 0; ii < 8; ii++) acc += a[ii]*x[ii];
    }
    for (; j < je; j++) {
        float a0 = __bfloat162float(akb[(size_t)j*768 + o*64 + lane]);
        acc += a0 * __bfloat162float(x_in[(size_t)srcOf[j]*768 + o*64 + lane]);
    }
    x1[(size_t)v*768 + o*64 + lane] = __float2bfloat16(acc);
}

// ---------------------------------------------------------------------------
// K5 (v13): node kernel — round-5 form (546us run): (256,8),
// per-lane-frag weights, inline union f2bf stores (no pointer escape).
// ---------------------------------------------------------------------------
#define ND_WREG2 2176
__global__ __launch_bounds__(256, 8) void node_mfma(
    const short* __restrict__ x1, const float* __restrict__ fk,
    const float* __restrict__ conv_b, const float* __restrict__ ln_g,
    const float* __restrict__ ln_b,
    const short* __restrict__ W1B, const float* __restrict__ b1,
    const short* __restrict__ W2B, const float* __restrict__ pb2,
    const float* __restrict__ Wr, const float* __restrict__ br,
    const __hip_bfloat16* __restrict__ x_old, __hip_bfloat16* __restrict__ x_new,
    float* __restrict__ racc, int has_res, int write_x, int lay)
{
    __shared__ short sU[4*ND_WREG2];

    int tid = threadIdx.x;
    int w   = tid >> 6;
    int blockRow = blockIdx.x * 64;
    short* reg = sU + w*ND_WREG2;

    // ---- Phase A: conv + LN, quarter-row (16 cols) per thread ----
    {
        int rl = tid >> 2;
        int qt = tid & 3;
        int lr = rl - 16*w;
        int row = blockRow + rl;                 // grid exact: row < N_ROWS
        int v = row / 12, pp = row % 12;
        float h[16];
        #pragma unroll
        for (int k = 0; k < 16; k++) h[k] = 0.f;
        const short* xv = x1 + (size_t)v*768 + qt*16;
        const float* fp = fk + (size_t)pp*768 + qt*16;
        #pragma unroll
        for (int o = 0; o < 12; o++) {
            const int4*  xa = (const int4*)(xv + o*64);
            const float4* fa = (const float4*)(fp + o*64);
            #pragma unroll
            for (int k4 = 0; k4 < 2; k4++) {
                int4 xi = xa[k4];
                float4 f0 = fa[2*k4], f1 = fa[2*k4+1];
                h[8*k4+0] += bflo((unsigned)xi.x)*f0.x; h[8*k4+1] += bfhi((unsigned)xi.x)*f0.y;
                h[8*k4+2] += bflo((unsigned)xi.y)*f0.z; h[8*k4+3] += bfhi((unsigned)xi.y)*f0.w;
                h[8*k4+4] += bflo((unsigned)xi.z)*f1.x; h[8*k4+5] += bfhi((unsigned)xi.z)*f1.y;
                h[8*k4+6] += bflo((unsigned)xi.w)*f1.z; h[8*k4+7] += bfhi((unsigned)xi.w)*f1.w;
            }
        }
        const float inv12 = 1.0f/12.0f;
        float sum = 0.f;
        #pragma unroll
        for (int k = 0; k < 16; k++) { h[k] = h[k]*inv12 + conv_b[qt*16 + k]; sum += h[k]; }
        sum += __shfl_xor(sum, 1);
        sum += __shfl_xor(sum, 2);
        float mu = sum * (1.0f/64.0f);
        float var = 0.f;
        #pragma unroll
        for (int k = 0; k < 16; k++) { float xc = h[k] - mu; var += xc*xc; }
        var += __shfl_xor(var, 1);
        var += __shfl_xor(var, 2);
        float rstd = rsqrtf(var*(1.0f/64.0f) + 1e-5f);
        short* dst = reg + lr*72 + qt*16;
        #pragma unroll
        for (int blk = 0; blk < 2; blk++) {
            union { short s[8]; int4 v4; } u;
            #pragma unroll
            for (int jj = 0; jj < 8; jj++) {
                int k = blk*8 + jj, c = qt*16 + k;
                u.s[jj] = f2bf((h[k] - mu)*rstd*ln_g[c] + ln_b[c]);
            }
            *(int4*)(dst + blk*8) = u.v4;
        }
    }
    __builtin_amdgcn_wave_barrier();

    int l   = tid & 63;
    int m16 = l & 15, q = l >> 4;

    bfrag a1[2];
    #pragma unroll
    for (int kc = 0; kc < 2; kc++)
        a1[kc] = *(const bfrag*)(reg + m16*72 + kc*32 + q*8);
    __builtin_amdgcn_wave_barrier();

    f32x4 acc2[4];
    #pragma unroll
    for (int n = 0; n < 4; n++) acc2[n] = (f32x4){0.f, 0.f, 0.f, 0.f};

    for (int ph = 0; ph < 2; ph++) {
        // FFN1 swapped: lane holds c = nt*16+q*4+r of row m16
        for (int ntl = 0; ntl < 8; ntl++) {
            int nt = ph*8 + ntl;
            f32x4 c0 = (f32x4){0.f,0.f,0.f,0.f};
            #pragma unroll
            for (int kc = 0; kc < 2; kc++) {
                bfrag bb = *(const bfrag*)(W1B + ((nt*2 + kc)*64 + l)*8);
                c0 = __builtin_amdgcn_mfma_f32_16x16x32_bf16(bb, a1[kc], c0, 0, 0, 0);
            }
            f32x4 b4 = *(const f32x4*)(b1 + nt*16 + q*4);
            int2 pk = pack4(gelu_f(c0[0] + b4[0]), gelu_f(c0[1] + b4[1]),
                            gelu_f(c0[2] + b4[2]), gelu_f(c0[3] + b4[3]));
            *(int2*)(reg + m16*136 + ntl*16 + q*4) = pk;
        }
        __builtin_amdgcn_wave_barrier();
        for (int kc2 = 0; kc2 < 4; kc2++) {
            bfrag a2 = *(const bfrag*)(reg + m16*136 + kc2*32 + q*8);
            #pragma unroll
            for (int nc = 0; nc < 4; nc++) {
                bfrag bb = *(const bfrag*)(W2B + (((nc*2 + ph)*4 + kc2)*64 + l)*8);
                acc2[nc] = __builtin_amdgcn_mfma_f32_16x16x32_bf16(bb, a2, acc2[nc], 0, 0, 0);
            }
        }
        __builtin_amdgcn_wave_barrier();
    }

    // ---- Epilogue: lane owns row (blockRow + 16w + m16), cols nc*16+q*4..+3
    int row = blockRow + 16*w + m16;
    float q0 = 0.f, q1 = 0.f;
    #pragma unroll
    for (int nc = 0; nc < 4; nc++) {
        int cb = nc*16 + q*4;
        f32x4 pb4 = *(const f32x4*)(pb2 + cb);
        float vals[4];
        #pragma unroll
        for (int r = 0; r < 4; r++) vals[r] = acc2[nc][r] + pb4[r];
        if (has_res) {
            int2 xo = *(const int2*)((const short*)x_old + (size_t)row*64 + cb);
            vals[0] += bflo((unsigned)xo.x); vals[1] += bfhi((unsigned)xo.x);
            vals[2] += bflo((unsigned)xo.y); vals[3] += bfhi((unsigned)xo.y);
        }
        if (write_x) {
            int2 pk = pack4(vals[0], vals[1], vals[2], vals[3]);
            *(int2*)((short*)x_new + (size_t)row*64 + cb) = pk;
        }
        f32x4 wr0 = *(const f32x4*)(Wr + 2*cb);
        f32x4 wr1 = *(const f32x4*)(Wr + 2*cb + 4);
        q0 += vals[0]*wr0[0] + vals[1]*wr0[2] + vals[2]*wr1[0] + vals[3]*wr1[2];
        q1 += vals[0]*wr0[1] + vals[1]*wr0[3] + vals[2]*wr1[1] + vals[3]*wr1[3];
    }
    q0 += __shfl_xor(q0, 16); q0 += __shfl_xor(q0, 32);
    q1 += __shfl_xor(q1, 16); q1 += __shfl_xor(q1, 32);
    if (q == 0) {
        racc[(size_t)row*4 + lay*2 + 0] = q0 + br[0];
        racc[(size_t)row*4 + lay*2 + 1] = q1 + br[1];
    }
}

// ---------------------------------------------------------------------------
// K6 (v3): readout — layer-separated racc, two-stage reduction (unchanged)
// ---------------------------------------------------------------------------
__global__ __launch_bounds__(256) void final_kernel(
    const float* __restrict__ racc, const float* __restrict__ ori,
    const int* __restrict__ batch, float* __restrict__ out)
{
    __shared__ float sAcc[64];
    int tid = threadIdx.x;
    if (tid < 64) sAcc[tid] = 0.f;
    __syncthreads();

    int v = blockIdx.x*256 + tid;
    if (v < N_NODES) {
        float srs = 0.f, vx = 0.f, vy = 0.f, vz = 0.f;
        #pragma unroll
        for (int p = 0; p < 12; p++) {
            const float* rr = racc + (size_t)(v*12 + p)*4;
            float r0 = rr[0] + rr[2];
            float r1 = rr[1] + rr[3];
            srs += r0;
            vx += r1*ori[3*p]; vy += r1*ori[3*p+1]; vz += r1*ori[3*p+2];
        }
        const float sc = 1.0f/24.0f;
        int g = batch[v];
        atomicAdd(&sAcc[g],            srs*sc);
        atomicAdd(&sAcc[16 + g*3 + 0], vx*sc);
        atomicAdd(&sAcc[16 + g*3 + 1], vy*sc);
        atomicAdd(&sAcc[16 + g*3 + 2], vz*sc);
    }
    __syncthreads();
    if (tid < 64) atomicAdd(&out[tid], sAcc[tid]);
}

extern "C" void kernel_launch(void* const* d_in, const int* in_sizes, int n_in,
                              void* d_out, int out_size, void* d_ws, size_t ws_size,
                              hipStream_t stream) {
    const float* pos    = (const float*)d_in[0];
    const float* f      = (const float*)d_in[1];
    const float* ori    = (const float*)d_in[2];
    const int*   ei     = (const int*)  d_in[3];
    const int*   batch  = (const int*)  d_in[4];
    const float* Wb1    = (const float*)d_in[5];
    const float* bb1    = (const float*)d_in[6];
    const float* Wb2    = (const float*)d_in[7];
    const float* bb2    = (const float*)d_in[8];
    const float* Wo1    = (const float*)d_in[9];
    const float* bo1    = (const float*)d_in[10];
    const float* Wo2    = (const float*)d_in[11];
    const float* bo2    = (const float*)d_in[12];
    const float* We     = (const float*)d_in[13];
    const float* Wk     = (const float*)d_in[14];
    const float* Wf     = (const float*)d_in[15];
    const float* conv_b = (const float*)d_in[16];
    const float* ln_g   = (const float*)d_in[17];
    const float* ln_b   = (const float*)d_in[18];
    const float* W1     = (const float*)d_in[19];
    const float* b1     = (const float*)d_in[20];
    const float* W2     = (const float*)d_in[21];
    const float* b2     = (const float*)d_in[22];
    const float* Wr     = (const float*)d_in[23];
    const float* br     = (const float*)d_in[24];
    float* out = (float*)d_out;

    float* ws   = (float*)d_ws;
    float* xe   = ws;                               //   640,000 f32
    short* xs1b = (short*)(xe + 640000);            // 7,680,000 bf16
    short* x1b  = xs1b + 7680000;                   // 7,680,000 bf16
    float* racc = (float*)(x1b + 7680000);          //   480,000 f32 (layered)
    float* fkb  = racc + 480000;                    //    18,432
    short* w1b  = (short*)(fkb + 18432);            //    32,768 shorts
    short* w2b  = w1b + 32768;
    short* w1k  = w2b + 32768;
    short* w2k  = w1k + 2048;
    short* wkb  = w2k + 4096;
    int*   deg  = (int*)(wkb + 8192);               //    10,000 ints
    int*   rp   = deg + 10000;
    int*   wp   = rp  + 10001;
    int*   dstO = wp  + 10000;                      // dst node per sorted slot
    int*   srcOf= dstO+ 80000;
    int*   pad_ = srcOf + 80000;
    __hip_bfloat16* akbA = (__hip_bfloat16*)(pad_ + 3);   // 61,440,000 bf16 (~123 MB)
    __hip_bfloat16* akbB = akbA + 61440000;               // second buffer (full mode)

    size_t need_full = ((char*)(akbB + 61440000)) - ((char*)d_ws);
    int full = (ws_size >= need_full) ? 1 : 0;

    hipMemsetAsync(out,  0, 64*sizeof(float), stream);
    hipMemsetAsync(deg,  0, 10000*sizeof(int), stream);

    csr_count<<<313, 256, 0, stream>>>(ei, deg);
    csr_scan <<<1,   256, 0, stream>>>(deg, rp, wp);
    csr_fill <<<313, 256, 0, stream>>>(ei, wp, dstO, srcOf);

    setup_kernel<<<2540, 256, 0, stream>>>(W1, W2, Wb1, Wb2, Wk,
                                           w1b, w2b, w1k, w2k, wkb,
                                           ori, Wo1, bo1, Wo2, bo2, Wf, fkb,
                                           f, We, xe);

    if (full) {
        kb_mfma <<<7500, 256, 0, stream>>>(pos, ori, w1k, bb1, w2k, bb2,
                                           wkb, akbA, wkb + 4096, akbB, /*dual=*/1, srcOf, dstO);
        gather0 <<<30000,256, 0, stream>>>(akbA, srcOf, rp, xe, (__hip_bfloat16*)x1b);
        node_mfma<<<1875,256, 0, stream>>>(x1b, fkb, conv_b, ln_g, ln_b,
                                           w1b, b1, w2b, b2, Wr, br,
                                           (const __hip_bfloat16*)xs1b, (__hip_bfloat16*)xs1b,
                                           racc, /*res=*/0, /*write=*/1, /*lay=*/0);
        gather1 <<<30000,256, 0, stream>>>(akbB, srcOf, rp,
                                           (const __hip_bfloat16*)xs1b, (__hip_bfloat16*)x1b);
    } else {
        kb_mfma <<<7500, 256, 0, stream>>>(pos, ori, w1k, bb1, w2k, bb2,
                                           wkb, akbA, wkb, akbA, /*dual=*/0, srcOf, dstO);
        gather0 <<<30000,256, 0, stream>>>(akbA, srcOf, rp, xe, (__hip_bfloat16*)x1b);
        node_mfma<<<1875,256, 0, stream>>>(x1b, fkb, conv_b, ln_g, ln_b,
                                           w1b, b1, w2b, b2, Wr, br,
                                           (const __hip_bfloat16*)xs1b, (__hip_bfloat16*)xs1b,
                                           racc, /*res=*/0, /*write=*/1, /*lay=*/0);
        kb_mfma <<<7500, 256, 0, stream>>>(pos, ori, w1k, bb1, w2k, bb2,
                                           wkb + 4096, akbA, wkb + 4096, akbA, /*dual=*/0, srcOf, dstO);
        gather1 <<<30000,256, 0, stream>>>(akbA, srcOf, rp,
                                           (const __hip_bfloat16*)xs1b, (__hip_bfloat16*)x1b);
    }

    node_mfma   <<<1875, 256, 0, stream>>>(x1b, fkb + 9216, conv_b + 64, ln_g + 64, ln_b + 64,
                                           w1b + 16384, b1 + 256, w2b + 16384, b2 + 64,
                                           Wr + 128, br + 2,
                                           (const __hip_bfloat16*)xs1b, (__hip_bfloat16*)xs1b,
                                           racc, /*res=*/1, /*write=*/0, /*lay=*/1);

    final_kernel<<<40,   256, 0, stream>>>(racc, ori, batch, out);
}